// Round 1
// baseline (253.833 us; speedup 1.0000x reference)
//
#include <hip/hip_runtime.h>

#define HW_ 65536
#define W_ 1024
#define H_ 64
#define B_ 2
#define C_ 68
#define NPIX 131072
#define EPS 1e-5f

typedef __attribute__((ext_vector_type(8))) short short8;
typedef __attribute__((ext_vector_type(4))) float floatx4;

__device__ __forceinline__ unsigned short f2bf(float f) {
  unsigned u = __float_as_uint(f);
  u += 0x7fffu + ((u >> 16) & 1u);
  return (unsigned short)(u >> 16);
}
__device__ __forceinline__ unsigned pack2(float a, float b) {
  return (unsigned)f2bf(a) | ((unsigned)f2bf(b) << 16);
}
__device__ __forceinline__ float wred(float v) {
  v += __shfl_xor(v, 1);  v += __shfl_xor(v, 2);  v += __shfl_xor(v, 4);
  v += __shfl_xor(v, 8);  v += __shfl_xor(v, 16); v += __shfl_xor(v, 32);
  return v;
}

// ---------------- K1: masked stats of pn@w1^T and pn@g1^T + counts ----------
__global__ __launch_bounds__(256) void k_stats1(
    const float* __restrict__ x, const float* __restrict__ mask,
    const float* __restrict__ w1, const float* __restrict__ g1,
    float* __restrict__ ws) {
  float acc[34];
#pragma unroll
  for (int i = 0; i < 34; i++) acc[i] = 0.f;

  for (int p = blockIdx.x * blockDim.x + threadIdx.x; p < NPIX;
       p += gridDim.x * blockDim.x) {
    int b = p >> 16, s = p & (HW_ - 1);
    int h = s >> 10, w = s & (W_ - 1);
    const float* xb = x + (size_t)b * C_ * HW_;
    const float* mb = mask + (size_t)b * HW_;
    float xc0 = xb[s], xc1 = xb[HW_ + s], xc2 = xb[2 * HW_ + s], xc3 = xb[3 * HW_ + s];
    acc[33] += (mb[s] > 0.f) ? 1.f : 0.f;
#pragma unroll
    for (int k = 0; k < 9; k++) {
      int di = k / 3 - 1, dj = k % 3 - 1;
      int hh = h + di, ww = w + dj;
      bool inb = ((unsigned)hh < (unsigned)H_) && ((unsigned)ww < (unsigned)W_);
      int ns = hh * W_ + ww;
      float mval = inb ? mb[ns] : 0.f;
      if (mval > 0.f) {  // inb guaranteed true here
        float pn0 = xb[ns] - xc0;
        float pn1 = xb[HW_ + ns] - xc1;
        float pn2 = xb[2 * HW_ + ns] - xc2;
        float pn3 = xb[3 * HW_ + ns] - xc3;
        acc[32] += 1.f;
#pragma unroll
        for (int o = 0; o < 8; o++) {
          float ta = pn0 * w1[o * 4] + pn1 * w1[o * 4 + 1] + pn2 * w1[o * 4 + 2] + pn3 * w1[o * 4 + 3];
          acc[o] += ta; acc[8 + o] += ta * ta;
          float tg = pn0 * g1[o * 4] + pn1 * g1[o * 4 + 1] + pn2 * g1[o * 4 + 2] + pn3 * g1[o * 4 + 3];
          acc[16 + o] += tg; acc[24 + o] += tg * tg;
        }
      }
    }
  }
  __shared__ float red[4][34];
  int lane = threadIdx.x & 63, wave = threadIdx.x >> 6;
#pragma unroll
  for (int i = 0; i < 34; i++) {
    float r = wred(acc[i]);
    if (lane == 0) red[wave][i] = r;
  }
  __syncthreads();
  if (threadIdx.x < 34)
    atomicAdd(&ws[threadIdx.x],
              red[0][threadIdx.x] + red[1][threadIdx.x] + red[2][threadIdx.x] + red[3][threadIdx.x]);
}

// ---------------- K2: masked stats of relu(gbn1(pn@g1^T)) @ g2^T ------------
__global__ __launch_bounds__(256) void k_stats2(
    const float* __restrict__ x, const float* __restrict__ mask,
    const float* __restrict__ g1, const float* __restrict__ gbn1_g,
    const float* __restrict__ gbn1_b, const float* __restrict__ g2,
    float* __restrict__ ws) {
  __shared__ float sc[8], sh[8];
  if (threadIdx.x < 8) {
    int o = threadIdx.x;
    float n = fmaxf(ws[32], 1.f);
    float mean = ws[16 + o] / n;
    float var = ws[24 + o] / n - mean * mean;
    float s = gbn1_g[o] * rsqrtf(var + EPS);
    sc[o] = s; sh[o] = gbn1_b[o] - mean * s;
  }
  __syncthreads();

  float acc[16];
#pragma unroll
  for (int i = 0; i < 16; i++) acc[i] = 0.f;

  for (int p = blockIdx.x * blockDim.x + threadIdx.x; p < NPIX;
       p += gridDim.x * blockDim.x) {
    int b = p >> 16, s = p & (HW_ - 1);
    int h = s >> 10, w = s & (W_ - 1);
    const float* xb = x + (size_t)b * C_ * HW_;
    const float* mb = mask + (size_t)b * HW_;
    float xc0 = xb[s], xc1 = xb[HW_ + s], xc2 = xb[2 * HW_ + s], xc3 = xb[3 * HW_ + s];
#pragma unroll
    for (int k = 0; k < 9; k++) {
      int di = k / 3 - 1, dj = k % 3 - 1;
      int hh = h + di, ww = w + dj;
      bool inb = ((unsigned)hh < (unsigned)H_) && ((unsigned)ww < (unsigned)W_);
      int ns = hh * W_ + ww;
      float mval = inb ? mb[ns] : 0.f;
      if (mval > 0.f) {
        float pn0 = xb[ns] - xc0;
        float pn1 = xb[HW_ + ns] - xc1;
        float pn2 = xb[2 * HW_ + ns] - xc2;
        float pn3 = xb[3 * HW_ + ns] - xc3;
        float gb[8];
#pragma unroll
        for (int o = 0; o < 8; o++) {
          float tg = pn0 * g1[o * 4] + pn1 * g1[o * 4 + 1] + pn2 * g1[o * 4 + 2] + pn3 * g1[o * 4 + 3];
          gb[o] = fmaxf(sc[o] * tg + sh[o], 0.f);
        }
#pragma unroll
        for (int j = 0; j < 8; j++) {
          float t2 = 0.f;
#pragma unroll
          for (int o = 0; o < 8; o++) t2 += gb[o] * g2[j * 8 + o];
          acc[j] += t2; acc[8 + j] += t2 * t2;
        }
      }
    }
  }
  __shared__ float red[4][16];
  int lane = threadIdx.x & 63, wave = threadIdx.x >> 6;
#pragma unroll
  for (int i = 0; i < 16; i++) {
    float r = wred(acc[i]);
    if (lane == 0) red[wave][i] = r;
  }
  __syncthreads();
  if (threadIdx.x < 16)
    atomicAdd(&ws[40 + threadIdx.x],
              red[0][threadIdx.x] + red[1][threadIdx.x] + red[2][threadIdx.x] + red[3][threadIdx.x]);
}

// ---------------- K3: per-pixel softmax weights, fagg, g-vector → bf16 vec --
__global__ __launch_bounds__(256) void k_main(
    const float* __restrict__ x, const float* __restrict__ mask,
    const float* __restrict__ w1, const float* __restrict__ bn1_g,
    const float* __restrict__ bn1_b, const float* __restrict__ w2,
    const float* __restrict__ b2, const float* __restrict__ g1,
    const float* __restrict__ gbn1_g, const float* __restrict__ gbn1_b,
    const float* __restrict__ g2, const float* __restrict__ gbn2_g,
    const float* __restrict__ gbn2_b, const float* __restrict__ ws,
    unsigned short* __restrict__ vec) {
  __shared__ float sA[8], hA[8], sG1[8], hG1[8], sG2[8], hG2[8];
  if (threadIdx.x < 24) {
    int o = threadIdx.x & 7;
    float n = fmaxf(ws[32], 1.f);
    float sum, sum2, gma, bta;
    if (threadIdx.x < 8)       { sum = ws[o];      sum2 = ws[8 + o];  gma = bn1_g[o];  bta = bn1_b[o]; }
    else if (threadIdx.x < 16) { sum = ws[16 + o]; sum2 = ws[24 + o]; gma = gbn1_g[o]; bta = gbn1_b[o]; }
    else                       { sum = ws[40 + o]; sum2 = ws[48 + o]; gma = gbn2_g[o]; bta = gbn2_b[o]; }
    float mean = sum / n, var = sum2 / n - mean * mean;
    float s = gma * rsqrtf(var + EPS);
    float sft = bta - mean * s;
    if (threadIdx.x < 8)       { sA[o] = s;  hA[o] = sft; }
    else if (threadIdx.x < 16) { sG1[o] = s; hG1[o] = sft; }
    else                       { sG2[o] = s; hG2[o] = sft; }
  }
  __syncthreads();

  int p = blockIdx.x * 256 + threadIdx.x;
  int b = p >> 16, s = p & (HW_ - 1);
  int h = s >> 10, w = s & (W_ - 1);
  const float* xb = x + (size_t)b * C_ * HW_;
  const float* mb = mask + (size_t)b * HW_;
  float xc0 = xb[s], xc1 = xb[HW_ + s], xc2 = xb[2 * HW_ + s], xc3 = xb[3 * HW_ + s];
  float b2v = b2[0];

  float ev[9]; int nsv[9]; bool inbv[9], mselv[9];
  float mx = -1e30f;
#pragma unroll
  for (int k = 0; k < 9; k++) {
    int di = k / 3 - 1, dj = k % 3 - 1;
    int hh = h + di, ww = w + dj;
    bool inb = ((unsigned)hh < (unsigned)H_) && ((unsigned)ww < (unsigned)W_);
    int ns = hh * W_ + ww;
    inbv[k] = inb; nsv[k] = ns;
    float mval = inb ? mb[ns] : 0.f;
    bool msel = mval > 0.f;
    mselv[k] = msel;
    float wp = 0.f;
    if (msel) {
      float pn0 = xb[ns] - xc0;
      float pn1 = xb[HW_ + ns] - xc1;
      float pn2 = xb[2 * HW_ + ns] - xc2;
      float pn3 = xb[3 * HW_ + ns] - xc3;
      float accw = 0.f;
#pragma unroll
      for (int o = 0; o < 8; o++) {
        float ta = pn0 * w1[o * 4] + pn1 * w1[o * 4 + 1] + pn2 * w1[o * 4 + 2] + pn3 * w1[o * 4 + 3];
        accw += fmaxf(sA[o] * ta + hA[o], 0.f) * w2[o];
      }
      wp = accw + b2v;
    }
    ev[k] = wp;
    mx = fmaxf(mx, wp);
  }
  float den = 0.f;
#pragma unroll
  for (int k = 0; k < 9; k++) { ev[k] = __expf(ev[k] - mx); den += ev[k]; }
  float inv = 1.f / den;

  float fagg[64];
#pragma unroll
  for (int c = 0; c < 64; c++) fagg[c] = 0.f;
  unsigned short* vrow = vec + (size_t)p * 160;

#pragma unroll
  for (int k = 0; k < 9; k++) {
    float wt = ev[k] * inv;
    int ns = nsv[k];
    uint4 pk; pk.x = pk.y = pk.z = pk.w = 0u;
    if (mselv[k]) {
      float pn0 = xb[ns] - xc0;
      float pn1 = xb[HW_ + ns] - xc1;
      float pn2 = xb[2 * HW_ + ns] - xc2;
      float pn3 = xb[3 * HW_ + ns] - xc3;
      float gb[8];
#pragma unroll
      for (int o = 0; o < 8; o++) {
        float tg = pn0 * g1[o * 4] + pn1 * g1[o * 4 + 1] + pn2 * g1[o * 4 + 2] + pn3 * g1[o * 4 + 3];
        gb[o] = fmaxf(sG1[o] * tg + hG1[o], 0.f);
      }
      float gv[8];
#pragma unroll
      for (int j = 0; j < 8; j++) {
        float t2 = 0.f;
#pragma unroll
        for (int o = 0; o < 8; o++) t2 += gb[o] * g2[j * 8 + o];
        float gg = fmaxf(sG2[j] * t2 + hG2[j], 0.f);
        gv[j] = wt * gg;
      }
      pk.x = pack2(gv[0], gv[1]); pk.y = pack2(gv[2], gv[3]);
      pk.z = pack2(gv[4], gv[5]); pk.w = pack2(gv[6], gv[7]);
    }
    *reinterpret_cast<uint4*>(vrow + 64 + k * 8) = pk;
    if (inbv[k]) {
      const float* xf = xb + 4 * HW_ + ns;
#pragma unroll
      for (int c = 0; c < 64; c++) fagg[c] += wt * xf[c * HW_];
    }
  }
#pragma unroll
  for (int c = 0; c < 64; c += 8) {
    uint4 pk;
    pk.x = pack2(fagg[c], fagg[c + 1]);     pk.y = pack2(fagg[c + 2], fagg[c + 3]);
    pk.z = pack2(fagg[c + 4], fagg[c + 5]); pk.w = pack2(fagg[c + 6], fagg[c + 7]);
    *reinterpret_cast<uint4*>(vrow + c) = pk;
  }
  uint4 z; z.x = z.y = z.z = z.w = 0u;
  *reinterpret_cast<uint4*>(vrow + 136) = z;
  *reinterpret_cast<uint4*>(vrow + 144) = z;
  *reinterpret_cast<uint4*>(vrow + 152) = z;
}

// ---------------- K4: MFMA GEMM (M=NPIX, N=64, K=160) + abn masked stats ----
__global__ __launch_bounds__(256) void k_gemm(
    const unsigned short* __restrict__ vec, const float* __restrict__ w_agg,
    const float* __restrict__ mask, float* __restrict__ out_pre,
    float* __restrict__ ws) {
  __shared__ uint4 Bf[4][5][64];
  for (int idx = threadIdx.x; idx < 4 * 5 * 64; idx += 256) {
    int lane = idx & 63;
    int ks = (idx >> 6) % 5;
    int nt = idx / 320;
    int n = nt * 16 + (lane & 15);
    int kb = ks * 32 + ((lane >> 4) << 3);
    unsigned short t[8];
#pragma unroll
    for (int j = 0; j < 8; j++) {
      int k = kb + j;
      float v = (k < 136) ? w_agg[n * 136 + k] : 0.f;
      t[j] = f2bf(v);
    }
    uint4 pk;
    pk.x = (unsigned)t[0] | ((unsigned)t[1] << 16);
    pk.y = (unsigned)t[2] | ((unsigned)t[3] << 16);
    pk.z = (unsigned)t[4] | ((unsigned)t[5] << 16);
    pk.w = (unsigned)t[6] | ((unsigned)t[7] << 16);
    Bf[nt][ks][lane] = pk;
  }
  __syncthreads();

  int lane = threadIdx.x & 63, wave = threadIdx.x >> 6;
  int gw = blockIdx.x * 4 + wave;  // 256 blocks * 4 waves = 1024
  float aS[4] = {0.f, 0.f, 0.f, 0.f}, aQ[4] = {0.f, 0.f, 0.f, 0.f};

  for (int mt = gw; mt < NPIX / 16; mt += 1024) {
    int p0 = mt * 16;
    const unsigned short* arow = vec + (size_t)(p0 + (lane & 15)) * 160 + ((lane >> 4) << 3);
    short8 A[5];
#pragma unroll
    for (int ks = 0; ks < 5; ks++)
      A[ks] = *reinterpret_cast<const short8*>(arow + ks * 32);
    int b = p0 >> 16;
    int srow = (p0 & (HW_ - 1)) + ((lane >> 4) << 2);
    float4 mv = *reinterpret_cast<const float4*>(mask + (size_t)b * HW_ + srow);
    float m0 = (mv.x > 0.f) ? 1.f : 0.f, m1 = (mv.y > 0.f) ? 1.f : 0.f;
    float m2 = (mv.z > 0.f) ? 1.f : 0.f, m3 = (mv.w > 0.f) ? 1.f : 0.f;
#pragma unroll
    for (int nt = 0; nt < 4; nt++) {
      floatx4 acc = {0.f, 0.f, 0.f, 0.f};
#pragma unroll
      for (int ks = 0; ks < 5; ks++) {
        short8 Bv = *reinterpret_cast<short8*>(&Bf[nt][ks][lane]);
        acc = __builtin_amdgcn_mfma_f32_16x16x32_bf16(A[ks], Bv, acc, 0, 0, 0);
      }
      int c = nt * 16 + (lane & 15);
      float4 ov;
      ov.x = acc[0]; ov.y = acc[1]; ov.z = acc[2]; ov.w = acc[3];
      aS[nt] += ov.x * m0 + ov.y * m1 + ov.z * m2 + ov.w * m3;
      aQ[nt] += ov.x * ov.x * m0 + ov.y * ov.y * m1 + ov.z * ov.z * m2 + ov.w * ov.w * m3;
      *reinterpret_cast<float4*>(out_pre + ((size_t)(b * 64 + c)) * HW_ + srow) = ov;
    }
  }

  __shared__ float rS[4][64], rQ[4][64];
#pragma unroll
  for (int nt = 0; nt < 4; nt++) {
    float v1 = aS[nt], v2 = aQ[nt];
    v1 += __shfl_xor(v1, 16); v1 += __shfl_xor(v1, 32);
    v2 += __shfl_xor(v2, 16); v2 += __shfl_xor(v2, 32);
    if (lane < 16) { rS[wave][nt * 16 + lane] = v1; rQ[wave][nt * 16 + lane] = v2; }
  }
  __syncthreads();
  if (threadIdx.x < 64) {
    atomicAdd(&ws[64 + threadIdx.x],
              rS[0][threadIdx.x] + rS[1][threadIdx.x] + rS[2][threadIdx.x] + rS[3][threadIdx.x]);
    atomicAdd(&ws[128 + threadIdx.x],
              rQ[0][threadIdx.x] + rQ[1][threadIdx.x] + rQ[2][threadIdx.x] + rQ[3][threadIdx.x]);
  }
}

// ---------------- K5: abn apply + relu + center-mask zero -------------------
__global__ __launch_bounds__(256) void k_final(
    const float* __restrict__ out_pre, const float* __restrict__ mask,
    const float* __restrict__ abn_g, const float* __restrict__ abn_b,
    const float* __restrict__ ws, float* __restrict__ out) {
  __shared__ float sc[64], sh[64];
  if (threadIdx.x < 64) {
    int c = threadIdx.x;
    float n0 = fmaxf(ws[33], 1.f);
    float mean = ws[64 + c] / n0;
    float var = ws[128 + c] / n0 - mean * mean;
    float s = abn_g[c] * rsqrtf(var + EPS);
    sc[c] = s; sh[c] = abn_b[c] - mean * s;
  }
  __syncthreads();
  int i4 = (blockIdx.x * 256 + threadIdx.x) * 4;
  if (i4 >= B_ * 64 * HW_) return;
  int c = (i4 >> 16) & 63;
  int b = i4 >> 22;
  int s = i4 & (HW_ - 1);
  float4 v = *reinterpret_cast<const float4*>(out_pre + i4);
  float4 m = *reinterpret_cast<const float4*>(mask + (size_t)b * HW_ + s);
  float4 o;
  o.x = (m.x > 0.f) ? fmaxf(v.x * sc[c] + sh[c], 0.f) : 0.f;
  o.y = (m.y > 0.f) ? fmaxf(v.y * sc[c] + sh[c], 0.f) : 0.f;
  o.z = (m.z > 0.f) ? fmaxf(v.z * sc[c] + sh[c], 0.f) : 0.f;
  o.w = (m.w > 0.f) ? fmaxf(v.w * sc[c] + sh[c], 0.f) : 0.f;
  *reinterpret_cast<float4*>(out + i4) = o;
}

extern "C" void kernel_launch(void* const* d_in, const int* in_sizes, int n_in,
                              void* d_out, int out_size, void* d_ws, size_t ws_size,
                              hipStream_t stream) {
  const float* x      = (const float*)d_in[0];
  const float* mask   = (const float*)d_in[1];
  const float* w1     = (const float*)d_in[2];
  const float* bn1_g  = (const float*)d_in[3];
  const float* bn1_b  = (const float*)d_in[4];
  const float* w2     = (const float*)d_in[5];
  const float* b2     = (const float*)d_in[6];
  const float* g1     = (const float*)d_in[7];
  const float* gbn1_g = (const float*)d_in[8];
  const float* gbn1_b = (const float*)d_in[9];
  const float* g2     = (const float*)d_in[10];
  const float* gbn2_g = (const float*)d_in[11];
  const float* gbn2_b = (const float*)d_in[12];
  const float* w_agg  = (const float*)d_in[13];
  const float* abn_g  = (const float*)d_in[14];
  const float* abn_b  = (const float*)d_in[15];
  float* out = (float*)d_out;

  size_t need = 1024 + (size_t)NPIX * 160 * 2 + (size_t)NPIX * 64 * 4;
  if (ws_size < need) return;  // insufficient scratch; would corrupt memory

  float* wsf = (float*)d_ws;
  unsigned short* vecb = (unsigned short*)((char*)d_ws + 1024);
  float* out_pre = (float*)((char*)d_ws + 1024 + (size_t)NPIX * 160 * 2);

  hipMemsetAsync(d_ws, 0, 1024, stream);
  k_stats1<<<256, 256, 0, stream>>>(x, mask, w1, g1, wsf);
  k_stats2<<<256, 256, 0, stream>>>(x, mask, g1, gbn1_g, gbn1_b, g2, wsf);
  k_main<<<512, 256, 0, stream>>>(x, mask, w1, bn1_g, bn1_b, w2, b2, g1,
                                  gbn1_g, gbn1_b, g2, gbn2_g, gbn2_b, wsf, vecb);
  k_gemm<<<256, 256, 0, stream>>>(vecb, w_agg, mask, out_pre, wsf);
  k_final<<<8192, 256, 0, stream>>>(out_pre, mask, abn_g, abn_b, wsf, out);
}

// Round 2
// 222.921 us; speedup vs baseline: 1.1387x; 1.1387x over previous
//
#include <hip/hip_runtime.h>

#define HW_ 65536
#define W_ 1024
#define H_ 64
#define B_ 2
#define C_ 68
#define NPIX 131072
#define EPS 1e-5f

typedef __attribute__((ext_vector_type(8))) short short8;
typedef __attribute__((ext_vector_type(4))) float floatx4;

__device__ __forceinline__ unsigned short f2bf(float f) {
  unsigned u = __float_as_uint(f);
  u += 0x7fffu + ((u >> 16) & 1u);
  return (unsigned short)(u >> 16);
}
__device__ __forceinline__ unsigned pack2(float a, float b) {
  return (unsigned)f2bf(a) | ((unsigned)f2bf(b) << 16);
}
__device__ __forceinline__ float wred(float v) {
  v += __shfl_xor(v, 1);  v += __shfl_xor(v, 2);  v += __shfl_xor(v, 4);
  v += __shfl_xor(v, 8);  v += __shfl_xor(v, 16); v += __shfl_xor(v, 32);
  return v;
}
__device__ __forceinline__ int swz_tile(int bid) {
  // XCD-contiguous: XCD j (= bid%8) owns tiles [j*64, j*64+64)
  return (bid & 7) * 64 + (bid >> 3);
}

// ---------------- K1: masked stats of pn@w1^T and pn@g1^T + counts ----------
__global__ __launch_bounds__(256) void k_stats1(
    const float* __restrict__ x, const float* __restrict__ mask,
    const float* __restrict__ w1, const float* __restrict__ g1,
    float* __restrict__ ws) {
  float acc[34];
#pragma unroll
  for (int i = 0; i < 34; i++) acc[i] = 0.f;

  int p = swz_tile(blockIdx.x) * 256 + threadIdx.x;
  {
    int b = p >> 16, s = p & (HW_ - 1);
    int h = s >> 10, w = s & (W_ - 1);
    const float* xb = x + (size_t)b * C_ * HW_;
    const float* mb = mask + (size_t)b * HW_;
    float xc0 = xb[s], xc1 = xb[HW_ + s], xc2 = xb[2 * HW_ + s], xc3 = xb[3 * HW_ + s];
    acc[33] += (mb[s] > 0.f) ? 1.f : 0.f;
#pragma unroll
    for (int k = 0; k < 9; k++) {
      int di = k / 3 - 1, dj = k % 3 - 1;
      int hh = h + di, ww = w + dj;
      bool inb = ((unsigned)hh < (unsigned)H_) && ((unsigned)ww < (unsigned)W_);
      int ns = hh * W_ + ww;
      float mval = inb ? mb[ns] : 0.f;
      if (mval > 0.f) {
        float pn0 = xb[ns] - xc0;
        float pn1 = xb[HW_ + ns] - xc1;
        float pn2 = xb[2 * HW_ + ns] - xc2;
        float pn3 = xb[3 * HW_ + ns] - xc3;
        acc[32] += 1.f;
#pragma unroll
        for (int o = 0; o < 8; o++) {
          float ta = pn0 * w1[o * 4] + pn1 * w1[o * 4 + 1] + pn2 * w1[o * 4 + 2] + pn3 * w1[o * 4 + 3];
          acc[o] += ta; acc[8 + o] += ta * ta;
          float tg = pn0 * g1[o * 4] + pn1 * g1[o * 4 + 1] + pn2 * g1[o * 4 + 2] + pn3 * g1[o * 4 + 3];
          acc[16 + o] += tg; acc[24 + o] += tg * tg;
        }
      }
    }
  }
  __shared__ float red[4][34];
  int lane = threadIdx.x & 63, wave = threadIdx.x >> 6;
#pragma unroll
  for (int i = 0; i < 34; i++) {
    float r = wred(acc[i]);
    if (lane == 0) red[wave][i] = r;
  }
  __syncthreads();
  if (threadIdx.x < 34)
    atomicAdd(&ws[threadIdx.x],
              red[0][threadIdx.x] + red[1][threadIdx.x] + red[2][threadIdx.x] + red[3][threadIdx.x]);
}

// ---------------- K2: masked stats of relu(gbn1(pn@g1^T)) @ g2^T ------------
__global__ __launch_bounds__(256) void k_stats2(
    const float* __restrict__ x, const float* __restrict__ mask,
    const float* __restrict__ g1, const float* __restrict__ gbn1_g,
    const float* __restrict__ gbn1_b, const float* __restrict__ g2,
    float* __restrict__ ws) {
  __shared__ float sc[8], sh[8];
  if (threadIdx.x < 8) {
    int o = threadIdx.x;
    float n = fmaxf(ws[32], 1.f);
    float mean = ws[16 + o] / n;
    float var = ws[24 + o] / n - mean * mean;
    float s = gbn1_g[o] * rsqrtf(var + EPS);
    sc[o] = s; sh[o] = gbn1_b[o] - mean * s;
  }
  __syncthreads();

  float acc[16];
#pragma unroll
  for (int i = 0; i < 16; i++) acc[i] = 0.f;

  int p = swz_tile(blockIdx.x) * 256 + threadIdx.x;
  {
    int b = p >> 16, s = p & (HW_ - 1);
    int h = s >> 10, w = s & (W_ - 1);
    const float* xb = x + (size_t)b * C_ * HW_;
    const float* mb = mask + (size_t)b * HW_;
    float xc0 = xb[s], xc1 = xb[HW_ + s], xc2 = xb[2 * HW_ + s], xc3 = xb[3 * HW_ + s];
#pragma unroll
    for (int k = 0; k < 9; k++) {
      int di = k / 3 - 1, dj = k % 3 - 1;
      int hh = h + di, ww = w + dj;
      bool inb = ((unsigned)hh < (unsigned)H_) && ((unsigned)ww < (unsigned)W_);
      int ns = hh * W_ + ww;
      float mval = inb ? mb[ns] : 0.f;
      if (mval > 0.f) {
        float pn0 = xb[ns] - xc0;
        float pn1 = xb[HW_ + ns] - xc1;
        float pn2 = xb[2 * HW_ + ns] - xc2;
        float pn3 = xb[3 * HW_ + ns] - xc3;
        float gb[8];
#pragma unroll
        for (int o = 0; o < 8; o++) {
          float tg = pn0 * g1[o * 4] + pn1 * g1[o * 4 + 1] + pn2 * g1[o * 4 + 2] + pn3 * g1[o * 4 + 3];
          gb[o] = fmaxf(sc[o] * tg + sh[o], 0.f);
        }
#pragma unroll
        for (int j = 0; j < 8; j++) {
          float t2 = 0.f;
#pragma unroll
          for (int o = 0; o < 8; o++) t2 += gb[o] * g2[j * 8 + o];
          acc[j] += t2; acc[8 + j] += t2 * t2;
        }
      }
    }
  }
  __shared__ float red[4][16];
  int lane = threadIdx.x & 63, wave = threadIdx.x >> 6;
#pragma unroll
  for (int i = 0; i < 16; i++) {
    float r = wred(acc[i]);
    if (lane == 0) red[wave][i] = r;
  }
  __syncthreads();
  if (threadIdx.x < 16)
    atomicAdd(&ws[40 + threadIdx.x],
              red[0][threadIdx.x] + red[1][threadIdx.x] + red[2][threadIdx.x] + red[3][threadIdx.x]);
}

// --------- K3: fused per-pixel vec build (LDS) + MFMA GEMM + abn stats ------
__global__ __launch_bounds__(256) void k_fused(
    const float* __restrict__ x, const float* __restrict__ mask,
    const float* __restrict__ w1, const float* __restrict__ bn1_g,
    const float* __restrict__ bn1_b, const float* __restrict__ w2,
    const float* __restrict__ b2, const float* __restrict__ g1,
    const float* __restrict__ gbn1_g, const float* __restrict__ gbn1_b,
    const float* __restrict__ g2, const float* __restrict__ gbn2_g,
    const float* __restrict__ gbn2_b, const float* __restrict__ w_agg,
    const float* __restrict__ ws, float* __restrict__ out_pre,
    float* __restrict__ wsum) {
  // K-major chunked tile: chunk c holds bf16 elements [8c, 8c+8) of each
  // pixel's 136-dim vector (fagg 0..63 = chunks 0..7, g 64..135 = 8..16).
  // Layout [chunk][pixel] -> both per-thread uint4 writes and MFMA A-frag
  // reads are the fully-coalesced (8-phase minimum) LDS pattern.
  __shared__ uint4 vecA[17][256];
  __shared__ float sA[8], hA[8], sG1[8], hG1[8], sG2[8], hG2[8];

  if (threadIdx.x < 24) {
    int o = threadIdx.x & 7;
    float n = fmaxf(ws[32], 1.f);
    float sum, sum2, gma, bta;
    if (threadIdx.x < 8)       { sum = ws[o];      sum2 = ws[8 + o];  gma = bn1_g[o];  bta = bn1_b[o]; }
    else if (threadIdx.x < 16) { sum = ws[16 + o]; sum2 = ws[24 + o]; gma = gbn1_g[o]; bta = gbn1_b[o]; }
    else                       { sum = ws[40 + o]; sum2 = ws[48 + o]; gma = gbn2_g[o]; bta = gbn2_b[o]; }
    float mean = sum / n, var = sum2 / n - mean * mean;
    float s = gma * rsqrtf(var + EPS);
    float sft = bta - mean * s;
    if (threadIdx.x < 8)       { sA[o] = s;  hA[o] = sft; }
    else if (threadIdx.x < 16) { sG1[o] = s; hG1[o] = sft; }
    else                       { sG2[o] = s; hG2[o] = sft; }
  }
  __syncthreads();

  int tile = swz_tile(blockIdx.x);
  int p0 = tile * 256;
  int p = p0 + threadIdx.x;
  int b = p >> 16, s = p & (HW_ - 1);
  int h = s >> 10, w = s & (W_ - 1);
  const float* xb = x + (size_t)b * C_ * HW_;
  const float* mb = mask + (size_t)b * HW_;
  float xc0 = xb[s], xc1 = xb[HW_ + s], xc2 = xb[2 * HW_ + s], xc3 = xb[3 * HW_ + s];
  float b2v = b2[0];

  float ev[9]; int nsv[9]; bool inbv[9], mselv[9];
  float mx = -1e30f;
#pragma unroll
  for (int k = 0; k < 9; k++) {
    int di = k / 3 - 1, dj = k % 3 - 1;
    int hh = h + di, ww = w + dj;
    bool inb = ((unsigned)hh < (unsigned)H_) && ((unsigned)ww < (unsigned)W_);
    int ns = hh * W_ + ww;
    inbv[k] = inb; nsv[k] = ns;
    float mval = inb ? mb[ns] : 0.f;
    bool msel = mval > 0.f;
    mselv[k] = msel;
    float wp = 0.f;
    if (msel) {
      float pn0 = xb[ns] - xc0;
      float pn1 = xb[HW_ + ns] - xc1;
      float pn2 = xb[2 * HW_ + ns] - xc2;
      float pn3 = xb[3 * HW_ + ns] - xc3;
      float accw = 0.f;
#pragma unroll
      for (int o = 0; o < 8; o++) {
        float ta = pn0 * w1[o * 4] + pn1 * w1[o * 4 + 1] + pn2 * w1[o * 4 + 2] + pn3 * w1[o * 4 + 3];
        accw += fmaxf(sA[o] * ta + hA[o], 0.f) * w2[o];
      }
      wp = accw + b2v;
    }
    ev[k] = wp;
    mx = fmaxf(mx, wp);
  }
  float den = 0.f;
#pragma unroll
  for (int k = 0; k < 9; k++) { ev[k] = __expf(ev[k] - mx); den += ev[k]; }
  float inv = 1.f / den;

  float fagg[64];
#pragma unroll
  for (int c = 0; c < 64; c++) fagg[c] = 0.f;

#pragma unroll
  for (int k = 0; k < 9; k++) {
    float wt = ev[k] * inv;
    int ns = nsv[k];
    uint4 pk; pk.x = pk.y = pk.z = pk.w = 0u;
    if (mselv[k]) {
      float pn0 = xb[ns] - xc0;
      float pn1 = xb[HW_ + ns] - xc1;
      float pn2 = xb[2 * HW_ + ns] - xc2;
      float pn3 = xb[3 * HW_ + ns] - xc3;
      float gb[8];
#pragma unroll
      for (int o = 0; o < 8; o++) {
        float tg = pn0 * g1[o * 4] + pn1 * g1[o * 4 + 1] + pn2 * g1[o * 4 + 2] + pn3 * g1[o * 4 + 3];
        gb[o] = fmaxf(sG1[o] * tg + hG1[o], 0.f);
      }
      float gv[8];
#pragma unroll
      for (int j = 0; j < 8; j++) {
        float t2 = 0.f;
#pragma unroll
        for (int o = 0; o < 8; o++) t2 += gb[o] * g2[j * 8 + o];
        float gg = fmaxf(sG2[j] * t2 + hG2[j], 0.f);
        gv[j] = wt * gg;
      }
      pk.x = pack2(gv[0], gv[1]); pk.y = pack2(gv[2], gv[3]);
      pk.z = pack2(gv[4], gv[5]); pk.w = pack2(gv[6], gv[7]);
    }
    vecA[8 + k][threadIdx.x] = pk;
    if (inbv[k]) {
      const float* xf = xb + 4 * HW_ + ns;
#pragma unroll
      for (int c = 0; c < 64; c++) fagg[c] += wt * xf[c * HW_];
    }
  }
#pragma unroll
  for (int c = 0; c < 64; c += 8) {
    uint4 pk;
    pk.x = pack2(fagg[c], fagg[c + 1]);     pk.y = pack2(fagg[c + 2], fagg[c + 3]);
    pk.z = pack2(fagg[c + 4], fagg[c + 5]); pk.w = pack2(fagg[c + 6], fagg[c + 7]);
    vecA[c >> 3][threadIdx.x] = pk;
  }
  __syncthreads();

  // ---- GEMM: D[pixel 256][chan 64] = vecA @ w_agg^T, 16x16x32 bf16 MFMA ----
  int lane = threadIdx.x & 63, wave = threadIdx.x >> 6;
  int q = lane >> 4, r = lane & 15;

  // B-fragments: lane holds B[k = ks*32 + q*8 + j][n = nt*16 + r], bf16.
  short8 Bf[4][5];
#pragma unroll
  for (int nt = 0; nt < 4; nt++) {
    int n = nt * 16 + r;
#pragma unroll
    for (int ks = 0; ks < 5; ks++) {
      int k0 = ks * 32 + q * 8;
      uint4 pk; pk.x = pk.y = pk.z = pk.w = 0u;
      if (k0 < 136) {
        float4 f0 = *reinterpret_cast<const float4*>(w_agg + n * 136 + k0);
        float4 f1 = *reinterpret_cast<const float4*>(w_agg + n * 136 + k0 + 4);
        pk.x = pack2(f0.x, f0.y); pk.y = pack2(f0.z, f0.w);
        pk.z = pack2(f1.x, f1.y); pk.w = pack2(f1.z, f1.w);
      }
      Bf[nt][ks] = *reinterpret_cast<short8*>(&pk);
    }
  }

  floatx4 acc[4][4];
#pragma unroll
  for (int m = 0; m < 4; m++)
#pragma unroll
    for (int nt = 0; nt < 4; nt++) acc[m][nt] = (floatx4){0.f, 0.f, 0.f, 0.f};

#pragma unroll
  for (int m = 0; m < 4; m++) {
    int mt = wave * 4 + m;
    int pix = mt * 16 + r;
    short8 Af[5];
#pragma unroll
    for (int ks = 0; ks < 5; ks++) {
      int chunk = ks * 4 + q;
      if (chunk < 17)
        Af[ks] = *reinterpret_cast<const short8*>(&vecA[chunk][pix]);
      else
        Af[ks] = (short8){0, 0, 0, 0, 0, 0, 0, 0};
    }
#pragma unroll
    for (int nt = 0; nt < 4; nt++)
#pragma unroll
      for (int ks = 0; ks < 5; ks++)
        acc[m][nt] = __builtin_amdgcn_mfma_f32_16x16x32_bf16(Af[ks], Bf[nt][ks], acc[m][nt], 0, 0, 0);
  }

  // stores + masked abn stats
  float aS[4] = {0.f, 0.f, 0.f, 0.f}, aQ[4] = {0.f, 0.f, 0.f, 0.f};
  int s0 = p0 & (HW_ - 1);
#pragma unroll
  for (int m = 0; m < 4; m++) {
    int mt = wave * 4 + m;
    int srow = s0 + mt * 16 + q * 4;
    float4 mv = *reinterpret_cast<const float4*>(mb + srow);
    float m0 = (mv.x > 0.f) ? 1.f : 0.f, m1 = (mv.y > 0.f) ? 1.f : 0.f;
    float m2 = (mv.z > 0.f) ? 1.f : 0.f, m3 = (mv.w > 0.f) ? 1.f : 0.f;
#pragma unroll
    for (int nt = 0; nt < 4; nt++) {
      int ch = nt * 16 + r;
      float4 ov;
      ov.x = acc[m][nt][0]; ov.y = acc[m][nt][1];
      ov.z = acc[m][nt][2]; ov.w = acc[m][nt][3];
      aS[nt] += ov.x * m0 + ov.y * m1 + ov.z * m2 + ov.w * m3;
      aQ[nt] += ov.x * ov.x * m0 + ov.y * ov.y * m1 + ov.z * ov.z * m2 + ov.w * ov.w * m3;
      *reinterpret_cast<float4*>(out_pre + ((size_t)(b * 64 + ch)) * HW_ + srow) = ov;
    }
  }

  __syncthreads();  // all vecA ds_reads done; reuse LDS for reduction
  float* rS = (float*)&vecA[0][0];          // [4][64]
  float* rQ = rS + 256;                     // [4][64]
#pragma unroll
  for (int nt = 0; nt < 4; nt++) {
    float v1 = aS[nt], v2 = aQ[nt];
    v1 += __shfl_xor(v1, 16); v1 += __shfl_xor(v1, 32);
    v2 += __shfl_xor(v2, 16); v2 += __shfl_xor(v2, 32);
    if (lane < 16) { rS[wave * 64 + nt * 16 + lane] = v1; rQ[wave * 64 + nt * 16 + lane] = v2; }
  }
  __syncthreads();
  if (threadIdx.x < 64) {
    atomicAdd(&wsum[64 + threadIdx.x],
              rS[threadIdx.x] + rS[64 + threadIdx.x] + rS[128 + threadIdx.x] + rS[192 + threadIdx.x]);
    atomicAdd(&wsum[128 + threadIdx.x],
              rQ[threadIdx.x] + rQ[64 + threadIdx.x] + rQ[128 + threadIdx.x] + rQ[192 + threadIdx.x]);
  }
}

// ---------------- K4: abn apply + relu + center-mask zero -------------------
__global__ __launch_bounds__(256) void k_final(
    const float* __restrict__ out_pre, const float* __restrict__ mask,
    const float* __restrict__ abn_g, const float* __restrict__ abn_b,
    const float* __restrict__ ws, float* __restrict__ out) {
  __shared__ float sc[64], sh[64];
  if (threadIdx.x < 64) {
    int c = threadIdx.x;
    float n0 = fmaxf(ws[33], 1.f);
    float mean = ws[64 + c] / n0;
    float var = ws[128 + c] / n0 - mean * mean;
    float s = abn_g[c] * rsqrtf(var + EPS);
    sc[c] = s; sh[c] = abn_b[c] - mean * s;
  }
  __syncthreads();
  int i4 = (blockIdx.x * 256 + threadIdx.x) * 4;
  if (i4 >= B_ * 64 * HW_) return;
  int c = (i4 >> 16) & 63;
  int b = i4 >> 22;
  int s = i4 & (HW_ - 1);
  float4 v = *reinterpret_cast<const float4*>(out_pre + i4);
  float4 m = *reinterpret_cast<const float4*>(mask + (size_t)b * HW_ + s);
  float4 o;
  o.x = (m.x > 0.f) ? fmaxf(v.x * sc[c] + sh[c], 0.f) : 0.f;
  o.y = (m.y > 0.f) ? fmaxf(v.y * sc[c] + sh[c], 0.f) : 0.f;
  o.z = (m.z > 0.f) ? fmaxf(v.z * sc[c] + sh[c], 0.f) : 0.f;
  o.w = (m.w > 0.f) ? fmaxf(v.w * sc[c] + sh[c], 0.f) : 0.f;
  *reinterpret_cast<float4*>(out + i4) = o;
}

extern "C" void kernel_launch(void* const* d_in, const int* in_sizes, int n_in,
                              void* d_out, int out_size, void* d_ws, size_t ws_size,
                              hipStream_t stream) {
  const float* x      = (const float*)d_in[0];
  const float* mask   = (const float*)d_in[1];
  const float* w1     = (const float*)d_in[2];
  const float* bn1_g  = (const float*)d_in[3];
  const float* bn1_b  = (const float*)d_in[4];
  const float* w2     = (const float*)d_in[5];
  const float* b2     = (const float*)d_in[6];
  const float* g1     = (const float*)d_in[7];
  const float* gbn1_g = (const float*)d_in[8];
  const float* gbn1_b = (const float*)d_in[9];
  const float* g2     = (const float*)d_in[10];
  const float* gbn2_g = (const float*)d_in[11];
  const float* gbn2_b = (const float*)d_in[12];
  const float* w_agg  = (const float*)d_in[13];
  const float* abn_g  = (const float*)d_in[14];
  const float* abn_b  = (const float*)d_in[15];
  float* out = (float*)d_out;

  size_t need = 1024 + (size_t)NPIX * 64 * 4;
  if (ws_size < need) return;

  float* wsf = (float*)d_ws;
  float* out_pre = (float*)((char*)d_ws + 1024);

  hipMemsetAsync(d_ws, 0, 1024, stream);
  k_stats1<<<512, 256, 0, stream>>>(x, mask, w1, g1, wsf);
  k_stats2<<<512, 256, 0, stream>>>(x, mask, g1, gbn1_g, gbn1_b, g2, wsf);
  k_fused<<<512, 256, 0, stream>>>(x, mask, w1, bn1_g, bn1_b, w2, b2, g1,
                                   gbn1_g, gbn1_b, g2, gbn2_g, gbn2_b, w_agg,
                                   wsf, out_pre, wsf);
  k_final<<<8192, 256, 0, stream>>>(out_pre, mask, abn_g, abn_b, wsf, out);
}